// Round 1
// baseline (714.735 us; speedup 1.0000x reference)
//
#include <hip/hip_runtime.h>

#define N_NODES 50000
#define N_EDGES 800000

// ---------------- degree count ----------------
__global__ __launch_bounds__(256) void k_count(const int* __restrict__ src,
                                               const int* __restrict__ dst,
                                               int* __restrict__ deg_out,
                                               int* __restrict__ deg_in) {
    int e = blockIdx.x * 256 + threadIdx.x;
    if (e < N_EDGES) {
        atomicAdd(&deg_out[src[e]], 1);
        atomicAdd(&deg_in[dst[e]], 1);
    }
}

// ---------------- norms ----------------
__global__ __launch_bounds__(256) void k_norm(const int* __restrict__ deg_out,
                                              const int* __restrict__ deg_in,
                                              float* __restrict__ norm_src,
                                              float* __restrict__ norm_dst) {
    int n = blockIdx.x * 256 + threadIdx.x;
    if (n < N_NODES) {
        int dO = deg_out[n]; if (dO < 1) dO = 1;
        int dI = deg_in[n];  if (dI < 1) dI = 1;
        norm_src[n] = rsqrtf((float)dO);
        norm_dst[n] = rsqrtf((float)dI);
    }
}

// ---------------- exclusive scan of deg_in (single block) ----------------
__global__ __launch_bounds__(256) void k_scan(const int* __restrict__ deg,
                                              int* __restrict__ row_start,
                                              int* __restrict__ cursor) {
    __shared__ int sm[256];
    __shared__ int carry_s;
    int t = threadIdx.x;
    if (t == 0) carry_s = 0;
    __syncthreads();
    for (int base = 0; base < N_NODES; base += 256) {
        int i = base + t;
        int v = (i < N_NODES) ? deg[i] : 0;
        sm[t] = v;
        __syncthreads();
        // Hillis-Steele inclusive scan
        for (int off = 1; off < 256; off <<= 1) {
            int tv = (t >= off) ? sm[t - off] : 0;
            __syncthreads();
            sm[t] += tv;
            __syncthreads();
        }
        int incl = sm[t];
        int carry = carry_s;
        if (i < N_NODES) {
            int excl = carry + incl - v;
            row_start[i] = excl;
            cursor[i] = excl;
        }
        __syncthreads();
        if (t == 255) carry_s = carry + sm[255];
        __syncthreads();
    }
    if (t == 0) row_start[N_NODES] = carry_s;
}

// ---------------- CSR fill ----------------
__global__ __launch_bounds__(256) void k_fill(const int* __restrict__ src,
                                              const int* __restrict__ dst,
                                              const float* __restrict__ norm_src,
                                              int* __restrict__ cursor,
                                              int* __restrict__ csr_src,
                                              float* __restrict__ csr_w) {
    int e = blockIdx.x * 256 + threadIdx.x;
    if (e < N_EDGES) {
        int d = dst[e], s = src[e];
        int pos = atomicAdd(&cursor[d], 1);
        csr_src[pos] = s;
        csr_w[pos] = norm_src[s];
    }
}

// ---------------- GEMM: G = X @ W, X is (N,128), W is (128,128) ----------------
__global__ __launch_bounds__(256) void k_gemm(const float* __restrict__ X,
                                              const float* __restrict__ W,
                                              float* __restrict__ G) {
    __shared__ float Wl[128 * 128];
#pragma unroll
    for (int it = 0; it < 16; ++it) {
        int i = threadIdx.x * 4 + it * 1024;
        *(float4*)&Wl[i] = *(const float4*)&W[i];
    }
    __syncthreads();
    const int tx = threadIdx.x & 15;
    const int ty = threadIdx.x >> 4;
    const int r0 = blockIdx.x * 64 + ty * 4;
    const int c0 = tx * 4;
    float acc[2][4][4] = {};
    for (int k = 0; k < 128; k += 4) {
        float4 xa[4];
#pragma unroll
        for (int i = 0; i < 4; ++i) {
            int r = r0 + i;
            xa[i] = (r < N_NODES) ? *(const float4*)(X + r * 128 + k)
                                  : make_float4(0.f, 0.f, 0.f, 0.f);
        }
#pragma unroll
        for (int kk = 0; kk < 4; ++kk) {
            float4 w0 = *(const float4*)&Wl[(k + kk) * 128 + c0];
            float4 w1 = *(const float4*)&Wl[(k + kk) * 128 + c0 + 64];
#pragma unroll
            for (int i = 0; i < 4; ++i) {
                float a = (kk == 0) ? xa[i].x : (kk == 1) ? xa[i].y
                         : (kk == 2) ? xa[i].z : xa[i].w;
                acc[0][i][0] = fmaf(a, w0.x, acc[0][i][0]);
                acc[0][i][1] = fmaf(a, w0.y, acc[0][i][1]);
                acc[0][i][2] = fmaf(a, w0.z, acc[0][i][2]);
                acc[0][i][3] = fmaf(a, w0.w, acc[0][i][3]);
                acc[1][i][0] = fmaf(a, w1.x, acc[1][i][0]);
                acc[1][i][1] = fmaf(a, w1.y, acc[1][i][1]);
                acc[1][i][2] = fmaf(a, w1.z, acc[1][i][2]);
                acc[1][i][3] = fmaf(a, w1.w, acc[1][i][3]);
            }
        }
    }
#pragma unroll
    for (int i = 0; i < 4; ++i) {
        int r = r0 + i;
        if (r < N_NODES) {
            *(float4*)(G + r * 128 + c0) =
                make_float4(acc[0][i][0], acc[0][i][1], acc[0][i][2], acc[0][i][3]);
            *(float4*)(G + r * 128 + c0 + 64) =
                make_float4(acc[1][i][0], acc[1][i][1], acc[1][i][2], acc[1][i][3]);
        }
    }
}

// ---------------- gather: Out[n] = act(norm_dst[n] * sum_e w_e * G[src_e] + b) ----------------
template <int ELU>
__global__ __launch_bounds__(256) void k_gather(const float* __restrict__ G,
                                                const int* __restrict__ row_start,
                                                const int* __restrict__ csr_src,
                                                const float* __restrict__ csr_w,
                                                const float* __restrict__ norm_dst,
                                                const float* __restrict__ bias,
                                                float* __restrict__ Out) {
    int n = (blockIdx.x * 256 + threadIdx.x) >> 6;
    int lane = threadIdx.x & 63;
    if (n >= N_NODES) return;
    int e0 = row_start[n], e1 = row_start[n + 1];
    float ax0 = 0.f, ay0 = 0.f, ax1 = 0.f, ay1 = 0.f;
    int e = e0;
    for (; e + 2 <= e1; e += 2) {
        int s0 = csr_src[e], s1 = csr_src[e + 1];
        float w0 = csr_w[e], w1 = csr_w[e + 1];
        float2 g0 = *(const float2*)(G + s0 * 128 + lane * 2);
        float2 g1 = *(const float2*)(G + s1 * 128 + lane * 2);
        ax0 = fmaf(w0, g0.x, ax0); ay0 = fmaf(w0, g0.y, ay0);
        ax1 = fmaf(w1, g1.x, ax1); ay1 = fmaf(w1, g1.y, ay1);
    }
    if (e < e1) {
        int s0 = csr_src[e];
        float w0 = csr_w[e];
        float2 g0 = *(const float2*)(G + s0 * 128 + lane * 2);
        ax0 = fmaf(w0, g0.x, ax0); ay0 = fmaf(w0, g0.y, ay0);
    }
    float nd = norm_dst[n];
    float2 b = *(const float2*)(bias + lane * 2);
    float ox = fmaf(nd, ax0 + ax1, b.x);
    float oy = fmaf(nd, ay0 + ay1, b.y);
    if (ELU) {
        ox = ox > 0.f ? ox : expm1f(ox);
        oy = oy > 0.f ? oy : expm1f(oy);
    }
    *(float2*)(Out + n * 128 + lane * 2) = make_float2(ox, oy);
}

// ---------------- final projection: n_out = embed @ W_out + b_out ----------------
__global__ __launch_bounds__(256) void k_out(const float* __restrict__ emb,
                                             const float* __restrict__ Wo,
                                             const float* __restrict__ bo,
                                             float* __restrict__ out) {
    int n = (blockIdx.x * 256 + threadIdx.x) >> 6;
    int lane = threadIdx.x & 63;
    if (n >= N_NODES) return;
    float2 v = *(const float2*)(emb + n * 128 + lane * 2);
    // W_out is (128,2) row-major; this lane covers k = 2*lane, 2*lane+1
    float a0 = v.x * Wo[lane * 4 + 0] + v.y * Wo[lane * 4 + 2];
    float a1 = v.x * Wo[lane * 4 + 1] + v.y * Wo[lane * 4 + 3];
#pragma unroll
    for (int off = 32; off > 0; off >>= 1) {
        a0 += __shfl_down(a0, off);
        a1 += __shfl_down(a1, off);
    }
    if (lane == 0) {
        out[n * 2 + 0] = a0 + bo[0];
        out[n * 2 + 1] = a1 + bo[1];
    }
}

extern "C" void kernel_launch(void* const* d_in, const int* in_sizes, int n_in,
                              void* d_out, int out_size, void* d_ws, size_t ws_size,
                              hipStream_t stream) {
    const float* x     = (const float*)d_in[0];
    const int*   src   = (const int*)d_in[1];
    const int*   dst   = (const int*)d_in[2];
    const float* W1    = (const float*)d_in[3];
    const float* b1    = (const float*)d_in[4];
    const float* W2    = (const float*)d_in[5];
    const float* b2    = (const float*)d_in[6];
    const float* W3    = (const float*)d_in[7];
    const float* b3    = (const float*)d_in[8];
    const float* W_out = (const float*)d_in[9];
    const float* b_out = (const float*)d_in[10];

    float* out = (float*)d_out;                 // n_out: N*2, then n_embed: N*128
    float* emb = out + (size_t)N_NODES * 2;

    char* ws = (char*)d_ws;
    const size_t P_N  = 200192;   // pad(N*4)
    const size_t P_E  = 3200000;  // E*4 (512-aligned)
    const size_t P_H  = 25600000; // N*128*4 (512-aligned)
    int*   deg_out  = (int*)(ws + 0);
    int*   deg_in   = (int*)(ws + P_N);
    float* norm_src = (float*)(ws + 2 * P_N);
    float* norm_dst = (float*)(ws + 3 * P_N);
    int*   row_start= (int*)(ws + 4 * P_N);
    int*   cursor   = (int*)(ws + 5 * P_N);
    int*   csr_src  = (int*)(ws + 6 * P_N);
    float* csr_w    = (float*)(ws + 6 * P_N + P_E);
    float* bufA     = (float*)(ws + 6 * P_N + 2 * P_E);
    float* bufB     = (float*)(ws + 6 * P_N + 2 * P_E + P_H);

    const int gridE = (N_EDGES + 255) / 256;        // 3125
    const int gridN = (N_NODES + 255) / 256;        // 196
    const int gridG = (N_NODES + 63) / 64;          // 782 (gemm)
    const int gridW = (N_NODES * 64 + 255) / 256;   // 12500 (wave per node)

    hipMemsetAsync(deg_out, 0, 2 * P_N, stream);    // deg_out + deg_in
    k_count<<<gridE, 256, 0, stream>>>(src, dst, deg_out, deg_in);
    k_norm<<<gridN, 256, 0, stream>>>(deg_out, deg_in, norm_src, norm_dst);
    k_scan<<<1, 256, 0, stream>>>(deg_in, row_start, cursor);
    k_fill<<<gridE, 256, 0, stream>>>(src, dst, norm_src, cursor, csr_src, csr_w);

    // layer 1: x -> bufA
    k_gemm<<<gridG, 256, 0, stream>>>(x, W1, bufB);
    k_gather<1><<<gridW, 256, 0, stream>>>(bufB, row_start, csr_src, csr_w,
                                           norm_dst, b1, bufA);
    // layer 2: bufA -> bufA
    k_gemm<<<gridG, 256, 0, stream>>>(bufA, W2, bufB);
    k_gather<1><<<gridW, 256, 0, stream>>>(bufB, row_start, csr_src, csr_w,
                                           norm_dst, b2, bufA);
    // layer 3: bufA -> emb (no activation)
    k_gemm<<<gridG, 256, 0, stream>>>(bufA, W3, bufB);
    k_gather<0><<<gridW, 256, 0, stream>>>(bufB, row_start, csr_src, csr_w,
                                           norm_dst, b3, emb);
    // projection
    k_out<<<gridW, 256, 0, stream>>>(emb, W_out, b_out, out);
}

// Round 3
// 508.614 us; speedup vs baseline: 1.4053x; 1.4053x over previous
//
#include <hip/hip_runtime.h>

#define N_NODES 50000
#define N_EDGES 800000
#define SCAN_BLOCKS 196  // ceil(N_NODES/256)

// ---------------- degree count ----------------
__global__ __launch_bounds__(256) void k_count(const int* __restrict__ src,
                                               const int* __restrict__ dst,
                                               int* __restrict__ deg_out,
                                               int* __restrict__ deg_in) {
    int e = blockIdx.x * 256 + threadIdx.x;
    if (e < N_EDGES) {
        atomicAdd(&deg_out[src[e]], 1);
        atomicAdd(&deg_in[dst[e]], 1);
    }
}

// ---------------- norms ----------------
__global__ __launch_bounds__(256) void k_norm(const int* __restrict__ deg_out,
                                              const int* __restrict__ deg_in,
                                              float* __restrict__ norm_src,
                                              float* __restrict__ norm_dst) {
    int n = blockIdx.x * 256 + threadIdx.x;
    if (n < N_NODES) {
        int dO = deg_out[n]; if (dO < 1) dO = 1;
        int dI = deg_in[n];  if (dI < 1) dI = 1;
        norm_src[n] = rsqrtf((float)dO);
        norm_dst[n] = rsqrtf((float)dI);
    }
}

// ---------------- two-level scan of deg_in ----------------
// scan1: per-block sums
__global__ __launch_bounds__(256) void k_scan1(const int* __restrict__ deg,
                                               int* __restrict__ partials) {
    __shared__ int sm[4];
    int i = blockIdx.x * 256 + threadIdx.x;
    int v = (i < N_NODES) ? deg[i] : 0;
#pragma unroll
    for (int off = 32; off > 0; off >>= 1) v += __shfl_down(v, off);
    int lane = threadIdx.x & 63, w = threadIdx.x >> 6;
    if (lane == 0) sm[w] = v;
    __syncthreads();
    if (threadIdx.x == 0)
        partials[blockIdx.x] = sm[0] + sm[1] + sm[2] + sm[3];
}

// scan2: single block exclusive-scans SCAN_BLOCKS partials in place
__global__ __launch_bounds__(256) void k_scan2(int* __restrict__ partials,
                                               int* __restrict__ row_start) {
    __shared__ int sm[256];
    int t = threadIdx.x;
    int v = (t < SCAN_BLOCKS) ? partials[t] : 0;
    sm[t] = v;
    __syncthreads();
#pragma unroll
    for (int off = 1; off < 256; off <<= 1) {
        int tv = (t >= off) ? sm[t - off] : 0;
        __syncthreads();
        sm[t] += tv;
        __syncthreads();
    }
    if (t < SCAN_BLOCKS) partials[t] = sm[t] - v;  // exclusive
    if (t == 0) row_start[N_NODES] = N_EDGES;
}

// scan3: local 256-elem scan + block offset -> row_start, cursor
__global__ __launch_bounds__(256) void k_scan3(const int* __restrict__ deg,
                                               const int* __restrict__ partials,
                                               int* __restrict__ row_start,
                                               int* __restrict__ cursor) {
    __shared__ int sm[256];
    int t = threadIdx.x;
    int i = blockIdx.x * 256 + t;
    int v = (i < N_NODES) ? deg[i] : 0;
    sm[t] = v;
    __syncthreads();
#pragma unroll
    for (int off = 1; off < 256; off <<= 1) {
        int tv = (t >= off) ? sm[t - off] : 0;
        __syncthreads();
        sm[t] += tv;
        __syncthreads();
    }
    if (i < N_NODES) {
        int excl = sm[t] - v + partials[blockIdx.x];
        row_start[i] = excl;
        cursor[i] = excl;
    }
}

// ---------------- CSR fill ----------------
__global__ __launch_bounds__(256) void k_fill(const int* __restrict__ src,
                                              const int* __restrict__ dst,
                                              const float* __restrict__ norm_src,
                                              int* __restrict__ cursor,
                                              int* __restrict__ csr_src,
                                              float* __restrict__ csr_w) {
    int e = blockIdx.x * 256 + threadIdx.x;
    if (e < N_EDGES) {
        int d = dst[e], s = src[e];
        int pos = atomicAdd(&cursor[d], 1);
        csr_src[pos] = s;
        csr_w[pos] = norm_src[s];
    }
}

// ---------------- GEMM: G = X @ W, X is (N,128), W is (128,128) ----------------
__global__ __launch_bounds__(256) void k_gemm(const float* __restrict__ X,
                                              const float* __restrict__ W,
                                              float* __restrict__ G) {
    __shared__ float Wl[128 * 128];
#pragma unroll
    for (int it = 0; it < 16; ++it) {
        int i = threadIdx.x * 4 + it * 1024;
        *(float4*)&Wl[i] = *(const float4*)&W[i];
    }
    __syncthreads();
    const int tx = threadIdx.x & 15;
    const int ty = threadIdx.x >> 4;
    const int r0 = blockIdx.x * 64 + ty * 4;
    const int c0 = tx * 4;
    float acc[2][4][4] = {};
    for (int k = 0; k < 128; k += 4) {
        float4 xa[4];
#pragma unroll
        for (int i = 0; i < 4; ++i) {
            int r = r0 + i;
            xa[i] = (r < N_NODES) ? *(const float4*)(X + r * 128 + k)
                                  : make_float4(0.f, 0.f, 0.f, 0.f);
        }
#pragma unroll
        for (int kk = 0; kk < 4; ++kk) {
            float4 w0 = *(const float4*)&Wl[(k + kk) * 128 + c0];
            float4 w1 = *(const float4*)&Wl[(k + kk) * 128 + c0 + 64];
#pragma unroll
            for (int i = 0; i < 4; ++i) {
                float a = (kk == 0) ? xa[i].x : (kk == 1) ? xa[i].y
                         : (kk == 2) ? xa[i].z : xa[i].w;
                acc[0][i][0] = fmaf(a, w0.x, acc[0][i][0]);
                acc[0][i][1] = fmaf(a, w0.y, acc[0][i][1]);
                acc[0][i][2] = fmaf(a, w0.z, acc[0][i][2]);
                acc[0][i][3] = fmaf(a, w0.w, acc[0][i][3]);
                acc[1][i][0] = fmaf(a, w1.x, acc[1][i][0]);
                acc[1][i][1] = fmaf(a, w1.y, acc[1][i][1]);
                acc[1][i][2] = fmaf(a, w1.z, acc[1][i][2]);
                acc[1][i][3] = fmaf(a, w1.w, acc[1][i][3]);
            }
        }
    }
#pragma unroll
    for (int i = 0; i < 4; ++i) {
        int r = r0 + i;
        if (r < N_NODES) {
            *(float4*)(G + r * 128 + c0) =
                make_float4(acc[0][i][0], acc[0][i][1], acc[0][i][2], acc[0][i][3]);
            *(float4*)(G + r * 128 + c0 + 64) =
                make_float4(acc[1][i][0], acc[1][i][1], acc[1][i][2], acc[1][i][3]);
        }
    }
}

// ---------------- gather: Out[n] = act(norm_dst[n] * sum_e w_e * G[src_e] + b) ----------------
template <int ELU>
__global__ __launch_bounds__(256) void k_gather(const float* __restrict__ G,
                                                const int* __restrict__ row_start,
                                                const int* __restrict__ csr_src,
                                                const float* __restrict__ csr_w,
                                                const float* __restrict__ norm_dst,
                                                const float* __restrict__ bias,
                                                float* __restrict__ Out) {
    int n = (blockIdx.x * 256 + threadIdx.x) >> 6;
    int lane = threadIdx.x & 63;
    if (n >= N_NODES) return;
    int e0 = row_start[n], e1 = row_start[n + 1];
    float ax0 = 0.f, ay0 = 0.f, ax1 = 0.f, ay1 = 0.f;
    int e = e0;
    for (; e + 2 <= e1; e += 2) {
        int s0 = csr_src[e], s1 = csr_src[e + 1];
        float w0 = csr_w[e], w1 = csr_w[e + 1];
        float2 g0 = *(const float2*)(G + s0 * 128 + lane * 2);
        float2 g1 = *(const float2*)(G + s1 * 128 + lane * 2);
        ax0 = fmaf(w0, g0.x, ax0); ay0 = fmaf(w0, g0.y, ay0);
        ax1 = fmaf(w1, g1.x, ax1); ay1 = fmaf(w1, g1.y, ay1);
    }
    if (e < e1) {
        int s0 = csr_src[e];
        float w0 = csr_w[e];
        float2 g0 = *(const float2*)(G + s0 * 128 + lane * 2);
        ax0 = fmaf(w0, g0.x, ax0); ay0 = fmaf(w0, g0.y, ay0);
    }
    float nd = norm_dst[n];
    float2 b = *(const float2*)(bias + lane * 2);
    float ox = fmaf(nd, ax0 + ax1, b.x);
    float oy = fmaf(nd, ay0 + ay1, b.y);
    if (ELU) {
        ox = ox > 0.f ? ox : expm1f(ox);
        oy = oy > 0.f ? oy : expm1f(oy);
    }
    *(float2*)(Out + n * 128 + lane * 2) = make_float2(ox, oy);
}

// ---------------- final projection: n_out = embed @ W_out + b_out ----------------
__global__ __launch_bounds__(256) void k_out(const float* __restrict__ emb,
                                             const float* __restrict__ Wo,
                                             const float* __restrict__ bo,
                                             float* __restrict__ out) {
    int n = (blockIdx.x * 256 + threadIdx.x) >> 6;
    int lane = threadIdx.x & 63;
    if (n >= N_NODES) return;
    float2 v = *(const float2*)(emb + n * 128 + lane * 2);
    // W_out is (128,2) row-major; this lane covers k = 2*lane, 2*lane+1
    float a0 = v.x * Wo[lane * 4 + 0] + v.y * Wo[lane * 4 + 2];
    float a1 = v.x * Wo[lane * 4 + 1] + v.y * Wo[lane * 4 + 3];
#pragma unroll
    for (int off = 32; off > 0; off >>= 1) {
        a0 += __shfl_down(a0, off);
        a1 += __shfl_down(a1, off);
    }
    if (lane == 0) {
        out[n * 2 + 0] = a0 + bo[0];
        out[n * 2 + 1] = a1 + bo[1];
    }
}

extern "C" void kernel_launch(void* const* d_in, const int* in_sizes, int n_in,
                              void* d_out, int out_size, void* d_ws, size_t ws_size,
                              hipStream_t stream) {
    const float* x     = (const float*)d_in[0];
    const int*   src   = (const int*)d_in[1];
    const int*   dst   = (const int*)d_in[2];
    const float* W1    = (const float*)d_in[3];
    const float* b1    = (const float*)d_in[4];
    const float* W2    = (const float*)d_in[5];
    const float* b2    = (const float*)d_in[6];
    const float* W3    = (const float*)d_in[7];
    const float* b3    = (const float*)d_in[8];
    const float* W_out = (const float*)d_in[9];
    const float* b_out = (const float*)d_in[10];

    float* out = (float*)d_out;                 // n_out: N*2, then n_embed: N*128
    float* emb = out + (size_t)N_NODES * 2;

    char* ws = (char*)d_ws;
    const size_t P_N  = 200192;   // pad(N*4)
    const size_t P_E  = 3200000;  // E*4 (512-aligned)
    const size_t P_H  = 25600000; // N*128*4 (512-aligned)
    int*   deg_out  = (int*)(ws + 0);
    int*   deg_in   = (int*)(ws + P_N);
    float* norm_src = (float*)(ws + 2 * P_N);
    float* norm_dst = (float*)(ws + 3 * P_N);
    int*   row_start= (int*)(ws + 4 * P_N);
    int*   cursor   = (int*)(ws + 5 * P_N);
    // deg_out is dead after k_norm; reuse its region for the scan partials.
    // (Round-2 bug: partials overlapped cursor -> OOB csr writes -> abort.)
    int*   partials = deg_out;
    int*   csr_src  = (int*)(ws + 6 * P_N);
    float* csr_w    = (float*)(ws + 6 * P_N + P_E);
    float* bufA     = (float*)(ws + 6 * P_N + 2 * P_E);
    float* bufB     = (float*)(ws + 6 * P_N + 2 * P_E + P_H);

    const int gridE = (N_EDGES + 255) / 256;        // 3125
    const int gridN = (N_NODES + 255) / 256;        // 196
    const int gridG = (N_NODES + 63) / 64;          // 782 (gemm)
    const int gridW = (N_NODES * 64 + 255) / 256;   // 12500 (wave per node)

    hipMemsetAsync(deg_out, 0, 2 * P_N, stream);    // deg_out + deg_in
    k_count<<<gridE, 256, 0, stream>>>(src, dst, deg_out, deg_in);
    k_norm<<<gridN, 256, 0, stream>>>(deg_out, deg_in, norm_src, norm_dst);
    k_scan1<<<SCAN_BLOCKS, 256, 0, stream>>>(deg_in, partials);
    k_scan2<<<1, 256, 0, stream>>>(partials, row_start);
    k_scan3<<<SCAN_BLOCKS, 256, 0, stream>>>(deg_in, partials, row_start, cursor);
    k_fill<<<gridE, 256, 0, stream>>>(src, dst, norm_src, cursor, csr_src, csr_w);

    // layer 1: x -> bufA
    k_gemm<<<gridG, 256, 0, stream>>>(x, W1, bufB);
    k_gather<1><<<gridW, 256, 0, stream>>>(bufB, row_start, csr_src, csr_w,
                                           norm_dst, b1, bufA);
    // layer 2: bufA -> bufA
    k_gemm<<<gridG, 256, 0, stream>>>(bufA, W2, bufB);
    k_gather<1><<<gridW, 256, 0, stream>>>(bufB, row_start, csr_src, csr_w,
                                           norm_dst, b2, bufA);
    // layer 3: bufA -> emb (no activation)
    k_gemm<<<gridG, 256, 0, stream>>>(bufA, W3, bufB);
    k_gather<0><<<gridW, 256, 0, stream>>>(bufB, row_start, csr_src, csr_w,
                                           norm_dst, b3, emb);
    // projection
    k_out<<<gridW, 256, 0, stream>>>(emb, W_out, b_out, out);
}